// Round 6
// baseline (310.109 us; speedup 1.0000x reference)
//
#include <hip/hip_runtime.h>

#define N_ELEM 4096
#define BLOCK 256
#define PER 16             // elems per thread
#define NG (PER / 2)       // v2f groups per thread
#define NWAVE (BLOCK / 64)
#define NITER 40
#define CAPACITY 600.0f
#define DAMPING 1e-3f

// Packed fp32: gfx950 has full-rate v_pk_{fma,mul,add,max}_f32. ext_vector
// arithmetic selects them (halves VALU issue count vs scalar — R5 measured
// ~51 op-eq/elem/iter, ~24 of which is packable math).
typedef float v2f __attribute__((ext_vector_type(2)));
union F4V2 { float4 f4; v2f v[2]; };

__device__ __forceinline__ float raw_rcp(float a) { return __builtin_amdgcn_rcpf(a); }
__device__ __forceinline__ v2f pk_rcp(v2f a) {
    v2f r; r.x = raw_rcp(a.x); r.y = raw_rcp(a.y); return r;
}
__device__ __forceinline__ v2f pk_max(v2f a, v2f b) { return __builtin_elementwise_max(a, b); }

__device__ __forceinline__ float bcast_first(float v) {
    return __uint_as_float(__builtin_amdgcn_readfirstlane(__float_as_uint(v)));
}

// Fused 2-value block sum-reduction. ONE barrier; parity buffer from caller.
__device__ __forceinline__ void block_reduce2(float& a, float& b, float* buf) {
    #pragma unroll
    for (int off = 32; off > 0; off >>= 1) {
        a += __shfl_xor(a, off, 64);
        b += __shfl_xor(b, off, 64);
    }
    const int wave = threadIdx.x >> 6;
    if ((threadIdx.x & 63) == 0) { buf[2 * wave] = a; buf[2 * wave + 1] = b; }
    __syncthreads();
    float a0 = 0.0f, b0 = 0.0f;
    #pragma unroll
    for (int i = 0; i < NWAVE; ++i) { a0 += buf[2 * i]; b0 += buf[2 * i + 1]; }
    a = a0; b = b0;
}

__device__ __forceinline__ float block_reduce_max(float v, float* buf) {
    #pragma unroll
    for (int off = 32; off > 0; off >>= 1) v = fmaxf(v, __shfl_xor(v, off, 64));
    const int wave = threadIdx.x >> 6;
    if ((threadIdx.x & 63) == 0) buf[wave] = v;
    __syncthreads();
    float m = buf[0];
    #pragma unroll
    for (int i = 1; i < NWAVE; ++i) m = fmaxf(m, buf[i]);
    return m;
}

// Pressure design (R1-R5): allocator caps this kernel near ~56-88 ARCH VGPRs
// and AGPR-splits the rest. Persistent reg state here = x,g,wih = 48 floats;
// c,w,tinv live in LDS (own-thread float4 slots, ds_read_b128, LDS pipe is
// idle). Packed fp32 halves the math issue count either way.
__global__ __launch_bounds__(BLOCK, 3) void ipm_knapsack_kernel(
        const float* __restrict__ costs,
        const float* __restrict__ weights,
        float* __restrict__ out) {
    __shared__ float4 c4s[N_ELEM / 4];    // 16 KB: -costs (this row)
    __shared__ float4 w4s[N_ELEM / 4];    // 16 KB: weights
    __shared__ float4 tis[N_ELEM / 4];    // 16 KB: per-iter 1/u scratch
    __shared__ float ldsA[2][2 * NWAVE];  // parity-buffered reduce scratch
    __shared__ float ldsM[2][NWAVE];
    const int row = blockIdx.x;
    const int t   = threadIdx.x;

    v2f x[NG], g[NG], wih[NG];

    // ---- Stage c (negated) and w into LDS; accumulate sum(w) ----
    const float4* cg = reinterpret_cast<const float4*>(costs + (size_t)row * N_ELEM);
    const float4* wg = reinterpret_cast<const float4*>(weights);
    float ws = 0.0f, zz = 0.0f;
    #pragma unroll
    for (int j = 0; j < NG / 2; ++j) {
        float4 cc = cg[t + BLOCK * j];
        float4 ww = wg[t + BLOCK * j];
        cc.x = -cc.x; cc.y = -cc.y; cc.z = -cc.z; cc.w = -cc.w;
        c4s[t + BLOCK * j] = cc;
        w4s[t + BLOCK * j] = ww;
        ws += (ww.x + ww.y) + (ww.z + ww.w);
    }
    block_reduce2(ws, zz, ldsA[0]);   // barrier also orders LDS staging

    const float x0 = CAPACITY / ws;
    #pragma unroll
    for (int k = 0; k < NG; ++k) { v2f x0v = {x0, x0}; x[k] = x0v; }
    float lam = 0.0f;
    // Newton identity: sum(w*dx) = -F2  =>  F2 <- (1-alpha)*F2 analytically.
    float f2 = fmaf(x0, ws, -CAPACITY);

    for (int it = 0; it <= NITER; ++it) {
        const float mu   = (it < 10) ? __uint_as_float((unsigned)(127 - it) << 23) : DAMPING;
        const float m2mu = -2.0f * mu;

        // ---- Phase A (packed): u=x(1-x); one rcp -> 1/u and 1/H=u^3*r ----
        v2f s1v = {0.0f, 0.0f}, s2v = {0.0f, 0.0f};
        #pragma unroll
        for (int j = 0; j < NG / 2; ++j) {
            F4V2 cv, wv, tv;
            cv.f4 = c4s[t + BLOCK * j];
            wv.f4 = w4s[t + BLOCK * j];
            #pragma unroll
            for (int h = 0; h < 2; ++h) {
                const int k = 2 * j + h;
                const v2f xk = x[k], wk = wv.v[h];
                const v2f p  = 1.0f - xk;
                const v2f u  = xk * p;
                const v2f d  = m2mu * u + mu;         // pk_fma: mu*(1-2u) > 0
                const v2f r  = pk_rcp(u * d);
                const v2f ti = r * d;                 // 1/u
                const v2f q  = xk - p;                // 2x-1
                const v2f f1 = (mu * ti) * q + (lam * wk + cv.v[h]);
                const v2f u2 = u * u;
                const v2f iH = (u2 * u) * r;          // 1/H
                const v2f gk = f1 * iH;
                const v2f wi = wk * iH;
                s1v = wk * gk + s1v;
                s2v = wk * wi + s2v;
                g[k] = gk; wih[k] = wi;
                tv.v[h] = ti;
            }
            tis[t + BLOCK * j] = tv.f4;
        }
        float s1 = s1v.x + s1v.y, s2 = s2v.x + s2v.y;
        block_reduce2(s1, s2, ldsA[(it + 1) & 1]);
        const float dlam = bcast_first((f2 - s1) * raw_rcp(s2));

        if (it == NITER) {
            float4* o4 = reinterpret_cast<float4*>(out + (size_t)row * N_ELEM);
            #pragma unroll
            for (int j = 0; j < NG / 2; ++j) {
                F4V2 ov;
                #pragma unroll
                for (int h = 0; h < 2; ++h) {
                    const int k = 2 * j + h;
                    const v2f dxn = dlam * wih[k] + g[k];
                    ov.v[h] = x[k] - dxn;
                }
                o4[t + BLOCK * j] = ov.f4;
            }
            return;
        }

        // ---- Phase B (packed): division-free fraction-to-boundary ----
        // dxn = -dx; min t = 1/max max(-dxn/(1-x), dxn/x);
        // 1/(1-x) = x*ti, 1/x = ti - x*ti. Store dxn into g[].
        v2f mv = {0.0f, 0.0f};
        #pragma unroll
        for (int j = 0; j < NG / 2; ++j) {
            F4V2 tv;
            tv.f4 = tis[t + BLOCK * j];
            #pragma unroll
            for (int h = 0; h < 2; ++h) {
                const int k = 2 * j + h;
                const v2f dxn = dlam * wih[k] + g[k];
                g[k] = dxn;
                const v2f ti = tv.v[h];
                const v2f xt = x[k] * ti;             // 1/(1-x)
                const v2f pt = ti - xt;               // 1/x
                mv = pk_max(mv, pk_max((-dxn) * xt, dxn * pt));
            }
        }
        float m = fmaxf(mv.x, mv.y);
        m = block_reduce_max(m, ldsM[it & 1]);
        const float alpha = bcast_first(fminf(1.0f, 0.99f * raw_rcp(m)));

        #pragma unroll
        for (int k = 0; k < NG; ++k) x[k] = (-alpha) * g[k] + x[k];
        lam = fmaf(alpha, dlam, lam);
        f2  = fmaf(-alpha, f2, f2);                   // F2 *= (1-alpha)
    }
}

extern "C" void kernel_launch(void* const* d_in, const int* in_sizes, int n_in,
                              void* d_out, int out_size, void* d_ws, size_t ws_size,
                              hipStream_t stream) {
    const float* costs   = (const float*)d_in[0];
    const float* weights = (const float*)d_in[1];
    float* out = (float*)d_out;
    const int B = in_sizes[0] / N_ELEM;   // 2048 rows
    ipm_knapsack_kernel<<<B, BLOCK, 0, stream>>>(costs, weights, out);
}

// Round 7
// 273.588 us; speedup vs baseline: 1.1335x; 1.1335x over previous
//
#include <hip/hip_runtime.h>

#define N_ELEM 4096
#define BLOCK 256
#define PER 16             // elems per thread
#define NG (PER / 2)       // v2f groups per thread
#define NWAVE (BLOCK / 64)
#define NITER 40
#define CAPACITY 600.0f
#define DAMPING 1e-3f
#define MU_FINAL_IT 10     // mus clamp to DAMPING from it=10 on
#define CONV_EPS 1e-5f     // m >= ||dx||_inf; tail movement << 2e-2 tol

typedef float v2f __attribute__((ext_vector_type(2)));
union F4V2 { float4 f4; v2f v[2]; };

__device__ __forceinline__ float raw_rcp(float a) { return __builtin_amdgcn_rcpf(a); }
__device__ __forceinline__ v2f pk_rcp(v2f a) {
    v2f r; r.x = raw_rcp(a.x); r.y = raw_rcp(a.y); return r;
}
__device__ __forceinline__ v2f pk_max(v2f a, v2f b) { return __builtin_elementwise_max(a, b); }

__device__ __forceinline__ float bcast_first(float v) {
    return __uint_as_float(__builtin_amdgcn_readfirstlane(__float_as_uint(v)));
}

// Fused 2-value block sum-reduction. ONE barrier; parity buffer from caller.
__device__ __forceinline__ void block_reduce2(float& a, float& b, float* buf) {
    #pragma unroll
    for (int off = 32; off > 0; off >>= 1) {
        a += __shfl_xor(a, off, 64);
        b += __shfl_xor(b, off, 64);
    }
    const int wave = threadIdx.x >> 6;
    if ((threadIdx.x & 63) == 0) { buf[2 * wave] = a; buf[2 * wave + 1] = b; }
    __syncthreads();
    float a0 = 0.0f, b0 = 0.0f;
    #pragma unroll
    for (int i = 0; i < NWAVE; ++i) { a0 += buf[2 * i]; b0 += buf[2 * i + 1]; }
    a = a0; b = b0;
}

__device__ __forceinline__ float block_reduce_max(float v, float* buf) {
    #pragma unroll
    for (int off = 32; off > 0; off >>= 1) v = fmaxf(v, __shfl_xor(v, off, 64));
    const int wave = threadIdx.x >> 6;
    if ((threadIdx.x & 63) == 0) buf[wave] = v;
    __syncthreads();
    float m = buf[0];
    #pragma unroll
    for (int i = 1; i < NWAVE; ++i) m = fmaxf(m, buf[i]);
    return m;
}

// R6 lesson: tis LDS round-trip cost occupancy (49.6KB -> 3 blk/CU) and
// lgkm stalls (VALUBusy 83->64%). Here: c,w in LDS (32KB, 4 blk/CU);
// x,g,wih,tinv in regs (64 fl + temps ~90 <= 128 budget from lb(256,4)).
__global__ __launch_bounds__(BLOCK, 4) void ipm_knapsack_kernel(
        const float* __restrict__ costs,
        const float* __restrict__ weights,
        float* __restrict__ out) {
    __shared__ float4 c4s[N_ELEM / 4];    // 16 KB: -costs (this row)
    __shared__ float4 w4s[N_ELEM / 4];    // 16 KB: weights
    __shared__ float ldsA[2][2 * NWAVE];  // parity-buffered reduce scratch
    __shared__ float ldsM[2][NWAVE];
    __shared__ float ldsF[2 * NWAVE];     // init + final-refine reduce
    const int row = blockIdx.x;
    const int t   = threadIdx.x;

    v2f x[NG], g[NG], wih[NG], tinv[NG];

    // ---- Stage c (negated) and w into LDS; accumulate sum(w) ----
    const float4* cg = reinterpret_cast<const float4*>(costs + (size_t)row * N_ELEM);
    const float4* wg = reinterpret_cast<const float4*>(weights);
    float ws = 0.0f, zz = 0.0f;
    #pragma unroll
    for (int j = 0; j < NG / 2; ++j) {
        float4 cc = cg[t + BLOCK * j];
        float4 ww = wg[t + BLOCK * j];
        cc.x = -cc.x; cc.y = -cc.y; cc.z = -cc.z; cc.w = -cc.w;
        c4s[t + BLOCK * j] = cc;
        w4s[t + BLOCK * j] = ww;
        ws += (ww.x + ww.y) + (ww.z + ww.w);
    }
    block_reduce2(ws, zz, ldsF);      // barrier also orders LDS staging

    const float x0 = CAPACITY / ws;
    #pragma unroll
    for (int k = 0; k < NG; ++k) { v2f x0v = {x0, x0}; x[k] = x0v; }
    float lam = 0.0f;
    // Newton identity: sum(w*dx) = -F2  =>  F2 <- (1-alpha)*F2 analytically.
    float f2 = fmaf(x0, ws, -CAPACITY);

    // Packed phase A: u=x(1-x); one rcp -> 1/u and 1/H=u^3*r.
    auto phaseA = [&](float mu, float& s1, float& s2) {
        const float m2mu = -2.0f * mu;
        v2f s1v = {0.0f, 0.0f}, s2v = {0.0f, 0.0f};
        #pragma unroll
        for (int j = 0; j < NG / 2; ++j) {
            F4V2 cv, wv;
            cv.f4 = c4s[t + BLOCK * j];
            wv.f4 = w4s[t + BLOCK * j];
            #pragma unroll
            for (int h = 0; h < 2; ++h) {
                const int k = 2 * j + h;
                const v2f xk = x[k], wk = wv.v[h];
                const v2f p  = 1.0f - xk;
                const v2f u  = xk * p;
                const v2f d  = m2mu * u + mu;         // mu*(1-2u) > 0
                const v2f r  = pk_rcp(u * d);
                const v2f ti = r * d;                 // 1/u
                const v2f q  = xk - p;                // 2x-1
                const v2f f1 = (mu * ti) * q + (lam * wk + cv.v[h]);
                const v2f u2 = u * u;
                const v2f iH = (u2 * u) * r;          // 1/H
                const v2f gk = f1 * iH;
                const v2f wi = wk * iH;
                s1v = wk * gk + s1v;
                s2v = wk * wi + s2v;
                g[k] = gk; wih[k] = wi; tinv[k] = ti;
            }
        }
        s1 = s1v.x + s1v.y; s2 = s2v.x + s2v.y;
    };

    for (int it = 0; it < NITER; ++it) {
        const float mu = (it < MU_FINAL_IT)
                       ? __uint_as_float((unsigned)(127 - it) << 23) : DAMPING;
        float s1, s2;
        phaseA(mu, s1, s2);
        block_reduce2(s1, s2, ldsA[(it + 1) & 1]);
        const float dlam = bcast_first((f2 - s1) * raw_rcp(s2));

        // ---- Phase B: division-free fraction-to-boundary ----
        // dxn = -dx; min t = 1/max max(-dxn/(1-x), dxn/x);
        // 1/(1-x) = x*ti, 1/x = ti - x*ti.  m >= ||dxn||_inf.
        v2f mv = {0.0f, 0.0f};
        #pragma unroll
        for (int k = 0; k < NG; ++k) {
            const v2f dxn = dlam * wih[k] + g[k];
            g[k] = dxn;
            const v2f ti = tinv[k];
            const v2f xt = x[k] * ti;                 // 1/(1-x)
            const v2f pt = ti - xt;                   // 1/x
            mv = pk_max(mv, pk_max((-dxn) * xt, dxn * pt));
        }
        float m = fmaxf(mv.x, mv.y);
        m = block_reduce_max(m, ldsM[it & 1]);        // block-uniform
        const float alpha = bcast_first(fminf(1.0f, 0.99f * raw_rcp(m)));

        #pragma unroll
        for (int k = 0; k < NG; ++k) x[k] = (-alpha) * g[k] + x[k];
        lam = fmaf(alpha, dlam, lam);
        f2  = fmaf(-alpha, f2, f2);                   // F2 *= (1-alpha)

        // Early convergence exit: mu is final (it>=10) and the applied full
        // Newton step had ||dx||_inf <= m < 1e-5. Reference's remaining
        // sweeps move x by <~1e-5 total (quadratic contraction) -- 2000x
        // below the 2e-2 tolerance. m is broadcast => uniform branch.
        if (it >= MU_FINAL_IT && m < CONV_EPS) break;
    }

    // ---- Final KKT refine at mu = DAMPING: out = x - (g + dlam*wih) ----
    float s1, s2;
    phaseA(DAMPING, s1, s2);
    block_reduce2(s1, s2, ldsF);
    const float dlam = bcast_first((f2 - s1) * raw_rcp(s2));

    float4* o4 = reinterpret_cast<float4*>(out + (size_t)row * N_ELEM);
    #pragma unroll
    for (int j = 0; j < NG / 2; ++j) {
        F4V2 ov;
        #pragma unroll
        for (int h = 0; h < 2; ++h) {
            const int k = 2 * j + h;
            const v2f dxn = dlam * wih[k] + g[k];
            ov.v[h] = x[k] - dxn;
        }
        o4[t + BLOCK * j] = ov.f4;
    }
}

extern "C" void kernel_launch(void* const* d_in, const int* in_sizes, int n_in,
                              void* d_out, int out_size, void* d_ws, size_t ws_size,
                              hipStream_t stream) {
    const float* costs   = (const float*)d_in[0];
    const float* weights = (const float*)d_in[1];
    float* out = (float*)d_out;
    const int B = in_sizes[0] / N_ELEM;   // 2048 rows
    ipm_knapsack_kernel<<<B, BLOCK, 0, stream>>>(costs, weights, out);
}

// Round 8
// 183.316 us; speedup vs baseline: 1.6917x; 1.4924x over previous
//
#include <hip/hip_runtime.h>

#define N_ELEM 4096
#define BLOCK 256
#define PER 16             // elems per thread
#define NG (PER / 2)       // v2f groups per thread
#define NWAVE (BLOCK / 64)
#define NITER 40
#define CAPACITY 600.0f
#define DAMPING 1e-3f
#define MU_FINAL_IT 10     // mus clamp to DAMPING from it=10 on
// R7 lesson: m has an fp32 noise floor ~2-5e-5 (F1 cancellation noise 1e-7
// over H~8e-3, amplified by 1/x) -> 1e-5 never fired. 1e-3 is safely above
// the floor and bounds the discarded tail movement by ~1.5e-3 << 2e-2 tol.
#define CONV_EPS 1e-3f

typedef float v2f __attribute__((ext_vector_type(2)));
union F4V2 { float4 f4; v2f v[2]; };

__device__ __forceinline__ float raw_rcp(float a) { return __builtin_amdgcn_rcpf(a); }
__device__ __forceinline__ v2f pk_rcp(v2f a) {
    v2f r; r.x = raw_rcp(a.x); r.y = raw_rcp(a.y); return r;
}
__device__ __forceinline__ v2f pk_max(v2f a, v2f b) { return __builtin_elementwise_max(a, b); }

__device__ __forceinline__ float bcast_first(float v) {
    return __uint_as_float(__builtin_amdgcn_readfirstlane(__float_as_uint(v)));
}

// Fused 2-value block sum-reduction. ONE barrier; parity buffer from caller.
__device__ __forceinline__ void block_reduce2(float& a, float& b, float* buf) {
    #pragma unroll
    for (int off = 32; off > 0; off >>= 1) {
        a += __shfl_xor(a, off, 64);
        b += __shfl_xor(b, off, 64);
    }
    const int wave = threadIdx.x >> 6;
    if ((threadIdx.x & 63) == 0) { buf[2 * wave] = a; buf[2 * wave + 1] = b; }
    __syncthreads();
    float a0 = 0.0f, b0 = 0.0f;
    #pragma unroll
    for (int i = 0; i < NWAVE; ++i) { a0 += buf[2 * i]; b0 += buf[2 * i + 1]; }
    a = a0; b = b0;
}

__device__ __forceinline__ float block_reduce_max(float v, float* buf) {
    #pragma unroll
    for (int off = 32; off > 0; off >>= 1) v = fmaxf(v, __shfl_xor(v, off, 64));
    const int wave = threadIdx.x >> 6;
    if ((threadIdx.x & 63) == 0) buf[wave] = v;
    __syncthreads();
    float m = buf[0];
    #pragma unroll
    for (int i = 1; i < NWAVE; ++i) m = fmaxf(m, buf[i]);
    return m;
}

// Layout (R6/R7 lessons): c,w in LDS (32KB, ds_read_b128, LDS pipe idle);
// x,g,wih,tinv in regs. Allocator AGPR-splits anyway (~52 arch + rest),
// but the op count is already packed-minimal; occupancy 3 blk/CU.
__global__ __launch_bounds__(BLOCK, 4) void ipm_knapsack_kernel(
        const float* __restrict__ costs,
        const float* __restrict__ weights,
        float* __restrict__ out) {
    __shared__ float4 c4s[N_ELEM / 4];    // 16 KB: -costs (this row)
    __shared__ float4 w4s[N_ELEM / 4];    // 16 KB: weights
    __shared__ float ldsA[2][2 * NWAVE];  // parity-buffered reduce scratch
    __shared__ float ldsM[2][NWAVE];
    __shared__ float ldsF[2 * NWAVE];     // init + final-refine reduce
    const int row = blockIdx.x;
    const int t   = threadIdx.x;

    v2f x[NG], g[NG], wih[NG], tinv[NG];

    // ---- Stage c (negated) and w into LDS; accumulate sum(w) ----
    const float4* cg = reinterpret_cast<const float4*>(costs + (size_t)row * N_ELEM);
    const float4* wg = reinterpret_cast<const float4*>(weights);
    float ws = 0.0f, zz = 0.0f;
    #pragma unroll
    for (int j = 0; j < NG / 2; ++j) {
        float4 cc = cg[t + BLOCK * j];
        float4 ww = wg[t + BLOCK * j];
        cc.x = -cc.x; cc.y = -cc.y; cc.z = -cc.z; cc.w = -cc.w;
        c4s[t + BLOCK * j] = cc;
        w4s[t + BLOCK * j] = ww;
        ws += (ww.x + ww.y) + (ww.z + ww.w);
    }
    block_reduce2(ws, zz, ldsF);      // barrier also orders LDS staging

    const float x0 = CAPACITY / ws;
    #pragma unroll
    for (int k = 0; k < NG; ++k) { v2f x0v = {x0, x0}; x[k] = x0v; }
    float lam = 0.0f;
    // Newton identity: sum(w*dx) = -F2  =>  F2 <- (1-alpha)*F2 analytically.
    float f2 = fmaf(x0, ws, -CAPACITY);

    // Packed phase A: u=x(1-x); one rcp -> 1/u and 1/H=u^3*r.
    auto phaseA = [&](float mu, float& s1, float& s2) {
        const float m2mu = -2.0f * mu;
        v2f s1v = {0.0f, 0.0f}, s2v = {0.0f, 0.0f};
        #pragma unroll
        for (int j = 0; j < NG / 2; ++j) {
            F4V2 cv, wv;
            cv.f4 = c4s[t + BLOCK * j];
            wv.f4 = w4s[t + BLOCK * j];
            #pragma unroll
            for (int h = 0; h < 2; ++h) {
                const int k = 2 * j + h;
                const v2f xk = x[k], wk = wv.v[h];
                const v2f p  = 1.0f - xk;
                const v2f u  = xk * p;
                const v2f d  = m2mu * u + mu;         // mu*(1-2u) > 0
                const v2f r  = pk_rcp(u * d);
                const v2f ti = r * d;                 // 1/u
                const v2f q  = xk - p;                // 2x-1
                const v2f f1 = (mu * ti) * q + (lam * wk + cv.v[h]);
                const v2f u2 = u * u;
                const v2f iH = (u2 * u) * r;          // 1/H
                const v2f gk = f1 * iH;
                const v2f wi = wk * iH;
                s1v = wk * gk + s1v;
                s2v = wk * wi + s2v;
                g[k] = gk; wih[k] = wi; tinv[k] = ti;
            }
        }
        s1 = s1v.x + s1v.y; s2 = s2v.x + s2v.y;
    };

    for (int it = 0; it < NITER; ++it) {
        const float mu = (it < MU_FINAL_IT)
                       ? __uint_as_float((unsigned)(127 - it) << 23) : DAMPING;
        float s1, s2;
        phaseA(mu, s1, s2);
        block_reduce2(s1, s2, ldsA[(it + 1) & 1]);
        const float dlam = bcast_first((f2 - s1) * raw_rcp(s2));

        // ---- Phase B: division-free fraction-to-boundary ----
        // dxn = -dx; min t = 1/max max(-dxn/(1-x), dxn/x);
        // 1/(1-x) = x*ti, 1/x = ti - x*ti.
        v2f mv = {0.0f, 0.0f};
        #pragma unroll
        for (int k = 0; k < NG; ++k) {
            const v2f dxn = dlam * wih[k] + g[k];
            g[k] = dxn;
            const v2f ti = tinv[k];
            const v2f xt = x[k] * ti;                 // 1/(1-x)
            const v2f pt = ti - xt;                   // 1/x
            mv = pk_max(mv, pk_max((-dxn) * xt, dxn * pt));
        }
        float m = fmaxf(mv.x, mv.y);
        m = block_reduce_max(m, ldsM[it & 1]);        // block-uniform
        const float alpha = bcast_first(fminf(1.0f, 0.99f * raw_rcp(m)));

        #pragma unroll
        for (int k = 0; k < NG; ++k) x[k] = (-alpha) * g[k] + x[k];
        lam = fmaf(alpha, dlam, lam);
        f2  = fmaf(-alpha, f2, f2);                   // F2 *= (1-alpha)

        // Early exit once mu is final and the applied step is tiny:
        // ||dx||_inf <= m*max(x,1-x) < CONV_EPS; geometric tail => the
        // reference's remaining sweeps move x by <~1.5*CONV_EPS, far under
        // the 2e-2 tolerance. m is broadcast => uniform branch, no diverge.
        if (it >= MU_FINAL_IT && m < CONV_EPS) break;
    }

    // ---- Final KKT refine at mu = DAMPING: out = x - (g + dlam*wih) ----
    float s1, s2;
    phaseA(DAMPING, s1, s2);
    block_reduce2(s1, s2, ldsF);
    const float dlam = bcast_first((f2 - s1) * raw_rcp(s2));

    float4* o4 = reinterpret_cast<float4*>(out + (size_t)row * N_ELEM);
    #pragma unroll
    for (int j = 0; j < NG / 2; ++j) {
        F4V2 ov;
        #pragma unroll
        for (int h = 0; h < 2; ++h) {
            const int k = 2 * j + h;
            const v2f dxn = dlam * wih[k] + g[k];
            ov.v[h] = x[k] - dxn;
        }
        o4[t + BLOCK * j] = ov.f4;
    }
}

extern "C" void kernel_launch(void* const* d_in, const int* in_sizes, int n_in,
                              void* d_out, int out_size, void* d_ws, size_t ws_size,
                              hipStream_t stream) {
    const float* costs   = (const float*)d_in[0];
    const float* weights = (const float*)d_in[1];
    float* out = (float*)d_out;
    const int B = in_sizes[0] / N_ELEM;   // 2048 rows
    ipm_knapsack_kernel<<<B, BLOCK, 0, stream>>>(costs, weights, out);
}

// Round 9
// 172.143 us; speedup vs baseline: 1.8015x; 1.0649x over previous
//
#include <hip/hip_runtime.h>

#define N_ELEM 4096
#define BLOCK 256
#define PER 16             // elems per thread
#define NG (PER / 2)       // v2f groups per thread
#define NWAVE (BLOCK / 64)
#define NITER 40
#define CAPACITY 600.0f
#define DAMPING 1e-3f
// R9: aggressive long-step homotopy. mu = 4^-it for it<5 (1, .25, .0625,
// .0156, .0039), then 1e-3. The mu=1e-3 barrier problem is strictly convex
// => unique minimizer => final output is path-independent; the m<eps exit
// gate (below) guarantees we only stop once damped Newton has converged at
// the final mu, so correctness does not depend on the schedule.
#define MU_FINAL_IT 5
// R7 lesson: m has an fp32 noise floor ~2-5e-5 -> 1e-5 never fired. 1e-3 is
// safely above it; discarded tail movement <~1.5e-3 << 2e-2 tolerance.
#define CONV_EPS 1e-3f

typedef float v2f __attribute__((ext_vector_type(2)));
union F4V2 { float4 f4; v2f v[2]; };

__device__ __forceinline__ float raw_rcp(float a) { return __builtin_amdgcn_rcpf(a); }
__device__ __forceinline__ v2f pk_rcp(v2f a) {
    v2f r; r.x = raw_rcp(a.x); r.y = raw_rcp(a.y); return r;
}
__device__ __forceinline__ v2f pk_max(v2f a, v2f b) { return __builtin_elementwise_max(a, b); }

__device__ __forceinline__ float bcast_first(float v) {
    return __uint_as_float(__builtin_amdgcn_readfirstlane(__float_as_uint(v)));
}

// Fused 2-value block sum-reduction. ONE barrier; parity buffer from caller.
__device__ __forceinline__ void block_reduce2(float& a, float& b, float* buf) {
    #pragma unroll
    for (int off = 32; off > 0; off >>= 1) {
        a += __shfl_xor(a, off, 64);
        b += __shfl_xor(b, off, 64);
    }
    const int wave = threadIdx.x >> 6;
    if ((threadIdx.x & 63) == 0) { buf[2 * wave] = a; buf[2 * wave + 1] = b; }
    __syncthreads();
    float a0 = 0.0f, b0 = 0.0f;
    #pragma unroll
    for (int i = 0; i < NWAVE; ++i) { a0 += buf[2 * i]; b0 += buf[2 * i + 1]; }
    a = a0; b = b0;
}

__device__ __forceinline__ float block_reduce_max(float v, float* buf) {
    #pragma unroll
    for (int off = 32; off > 0; off >>= 1) v = fmaxf(v, __shfl_xor(v, off, 64));
    const int wave = threadIdx.x >> 6;
    if ((threadIdx.x & 63) == 0) buf[wave] = v;
    __syncthreads();
    float m = buf[0];
    #pragma unroll
    for (int i = 1; i < NWAVE; ++i) m = fmaxf(m, buf[i]);
    return m;
}

// Layout (R6/R7 lessons): c,w in LDS (32KB, ds_read_b128, LDS pipe idle);
// x,g,wih,tinv in regs. Allocator AGPR-splits anyway (~52 arch + rest);
// occupancy ~3 blk/CU, VALUBusy ~67% — the sweep is packed-minimal, so R9
// attacks sweep COUNT (schedule), not sweep cost.
__global__ __launch_bounds__(BLOCK, 4) void ipm_knapsack_kernel(
        const float* __restrict__ costs,
        const float* __restrict__ weights,
        float* __restrict__ out) {
    __shared__ float4 c4s[N_ELEM / 4];    // 16 KB: -costs (this row)
    __shared__ float4 w4s[N_ELEM / 4];    // 16 KB: weights
    __shared__ float ldsA[2][2 * NWAVE];  // parity-buffered reduce scratch
    __shared__ float ldsM[2][NWAVE];
    __shared__ float ldsF[2 * NWAVE];     // init + final-refine reduce
    const int row = blockIdx.x;
    const int t   = threadIdx.x;

    v2f x[NG], g[NG], wih[NG], tinv[NG];

    // ---- Stage c (negated) and w into LDS; accumulate sum(w) ----
    const float4* cg = reinterpret_cast<const float4*>(costs + (size_t)row * N_ELEM);
    const float4* wg = reinterpret_cast<const float4*>(weights);
    float ws = 0.0f, zz = 0.0f;
    #pragma unroll
    for (int j = 0; j < NG / 2; ++j) {
        float4 cc = cg[t + BLOCK * j];
        float4 ww = wg[t + BLOCK * j];
        cc.x = -cc.x; cc.y = -cc.y; cc.z = -cc.z; cc.w = -cc.w;
        c4s[t + BLOCK * j] = cc;
        w4s[t + BLOCK * j] = ww;
        ws += (ww.x + ww.y) + (ww.z + ww.w);
    }
    block_reduce2(ws, zz, ldsF);      // barrier also orders LDS staging

    const float x0 = CAPACITY / ws;
    #pragma unroll
    for (int k = 0; k < NG; ++k) { v2f x0v = {x0, x0}; x[k] = x0v; }
    float lam = 0.0f;
    // Newton identity: sum(w*dx) = -F2  =>  F2 <- (1-alpha)*F2 analytically.
    float f2 = fmaf(x0, ws, -CAPACITY);

    // Packed phase A: u=x(1-x); one rcp -> 1/u and 1/H=u^3*r.
    auto phaseA = [&](float mu, float& s1, float& s2) {
        const float m2mu = -2.0f * mu;
        v2f s1v = {0.0f, 0.0f}, s2v = {0.0f, 0.0f};
        #pragma unroll
        for (int j = 0; j < NG / 2; ++j) {
            F4V2 cv, wv;
            cv.f4 = c4s[t + BLOCK * j];
            wv.f4 = w4s[t + BLOCK * j];
            #pragma unroll
            for (int h = 0; h < 2; ++h) {
                const int k = 2 * j + h;
                const v2f xk = x[k], wk = wv.v[h];
                const v2f p  = 1.0f - xk;
                const v2f u  = xk * p;
                const v2f d  = m2mu * u + mu;         // mu*(1-2u) > 0
                const v2f r  = pk_rcp(u * d);
                const v2f ti = r * d;                 // 1/u
                const v2f q  = xk - p;                // 2x-1
                const v2f f1 = (mu * ti) * q + (lam * wk + cv.v[h]);
                const v2f u2 = u * u;
                const v2f iH = (u2 * u) * r;          // 1/H
                const v2f gk = f1 * iH;
                const v2f wi = wk * iH;
                s1v = wk * gk + s1v;
                s2v = wk * wi + s2v;
                g[k] = gk; wih[k] = wi; tinv[k] = ti;
            }
        }
        s1 = s1v.x + s1v.y; s2 = s2v.x + s2v.y;
    };

    for (int it = 0; it < NITER; ++it) {
        // mu = 4^-it for it<5, else DAMPING (exact via exponent bits).
        const float mu = (it < MU_FINAL_IT)
                       ? __uint_as_float((unsigned)(127 - 2 * it) << 23) : DAMPING;
        float s1, s2;
        phaseA(mu, s1, s2);
        block_reduce2(s1, s2, ldsA[(it + 1) & 1]);
        const float dlam = bcast_first((f2 - s1) * raw_rcp(s2));

        // ---- Phase B: division-free fraction-to-boundary ----
        // dxn = -dx; min t = 1/max max(-dxn/(1-x), dxn/x);
        // 1/(1-x) = x*ti, 1/x = ti - x*ti.
        v2f mv = {0.0f, 0.0f};
        #pragma unroll
        for (int k = 0; k < NG; ++k) {
            const v2f dxn = dlam * wih[k] + g[k];
            g[k] = dxn;
            const v2f ti = tinv[k];
            const v2f xt = x[k] * ti;                 // 1/(1-x)
            const v2f pt = ti - xt;                   // 1/x
            mv = pk_max(mv, pk_max((-dxn) * xt, dxn * pt));
        }
        float m = fmaxf(mv.x, mv.y);
        m = block_reduce_max(m, ldsM[it & 1]);        // block-uniform
        const float alpha = bcast_first(fminf(1.0f, 0.99f * raw_rcp(m)));

        #pragma unroll
        for (int k = 0; k < NG; ++k) x[k] = (-alpha) * g[k] + x[k];
        lam = fmaf(alpha, dlam, lam);
        f2  = fmaf(-alpha, f2, f2);                   // F2 *= (1-alpha)

        // Exit once mu is final and the applied step is tiny: the mu=1e-3
        // minimizer is unique, so converged-at-final-mu == reference output
        // regardless of the path taken. m broadcast => uniform branch.
        if (it >= MU_FINAL_IT && m < CONV_EPS) break;
    }

    // ---- Final KKT refine at mu = DAMPING: out = x - (g + dlam*wih) ----
    float s1, s2;
    phaseA(DAMPING, s1, s2);
    block_reduce2(s1, s2, ldsF);
    const float dlam = bcast_first((f2 - s1) * raw_rcp(s2));

    float4* o4 = reinterpret_cast<float4*>(out + (size_t)row * N_ELEM);
    #pragma unroll
    for (int j = 0; j < NG / 2; ++j) {
        F4V2 ov;
        #pragma unroll
        for (int h = 0; h < 2; ++h) {
            const int k = 2 * j + h;
            const v2f dxn = dlam * wih[k] + g[k];
            ov.v[h] = x[k] - dxn;
        }
        o4[t + BLOCK * j] = ov.f4;
    }
}

extern "C" void kernel_launch(void* const* d_in, const int* in_sizes, int n_in,
                              void* d_out, int out_size, void* d_ws, size_t ws_size,
                              hipStream_t stream) {
    const float* costs   = (const float*)d_in[0];
    const float* weights = (const float*)d_in[1];
    float* out = (float*)d_out;
    const int B = in_sizes[0] / N_ELEM;   // 2048 rows
    ipm_knapsack_kernel<<<B, BLOCK, 0, stream>>>(costs, weights, out);
}